// Round 18
// baseline (551.559 us; speedup 1.0000x reference)
//
#include <hip/hip_runtime.h>

// Conv3d(8->32, k=3, VALID) + bias + HardSwish + GroupNorm(4) + mean pool.
// R13 = R12 (conv 69us, total 141.8: 256 thr, 4z x 4y, 28.8KB LDS, 2304
// blocks, one ds_read_b128 per K-chunk) + three measured-mechanism changes:
//  1. gn_finalize fused into conv's last block (R10-validated pattern);
//     3 dispatches -> 2: ~10us of the measured ~65us fixed overhead.
//  2. __launch_bounds__(256,4) (arg2 = min BLOCKS/CU, measured R8/R9):
//     requests 4-block residency, caps VGPR 128 (current 112 fits).
//  3. s_setprio(1) around tile MFMA bursts: blocks are barrier-free in the
//     loop -> phase diversity exists (T5 prerequisite; R12 occupancy 5.7
//     waves/CU means staging of one block should hide under others' compute).
// Diagnostic: OccupancyPercent. Rises -> residency was the stall; flat ->
// counter unreliable, pivot to staging vectorization.

#define IN 48
#define IN2 2304
#define IN3 110592
#define OUTD 46
#define RS 200            // row stride in dwords (50 e-slots x 4; overread fits)
#define NROW 36           // 6 z-rows x 6 y-rows
#define WPK_OFF 1024      // dword offset of packed-weight table inside ws
#define CNT_OFF 8192      // dword offset of block-completion counter
#define NBLK (16*12*12)

typedef short v8s   __attribute__((ext_vector_type(8)));
typedef float f32x4 __attribute__((ext_vector_type(4)));
typedef int   i32x4 __attribute__((ext_vector_type(4)));

__device__ __forceinline__ unsigned short f2bf(float f) {
    unsigned u = __builtin_bit_cast(unsigned, f);
    return (unsigned short)((u + 0x7fffu + ((u >> 16) & 1u)) >> 16);   // RNE
}
__device__ __forceinline__ float bf2f(unsigned short h) {
    unsigned u = ((unsigned)h) << 16;
    return __builtin_bit_cast(float, u);
}

// Tap-major A fragments for 16x16x32 (HW-validated R8/R12).
// Layout: [h][hl][c 0..6][lane][4 dw]. Lane: co_local = lane&15,
// kq = lane>>4 -> tau = 4c+kq; dword j = ci pair {2j, 2j+1}. tau>=27 -> 0.
// Also zeroes ws1/ws2 (gid<1024) and cnt (gid==1024).
__global__ __launch_bounds__(256) void pack_weights(
    const float* __restrict__ w, unsigned* __restrict__ wpk,
    float* __restrict__ wsz)
{
    int gid = blockIdx.x * 256 + threadIdx.x;
    if (gid < 1024) wsz[gid] = 0.f;
    if (gid == 1024) ((unsigned*)wsz)[CNT_OFF] = 0u;
    if (gid >= 1792) return;
    int lane = gid & 63;
    int rest = gid >> 6;          // 0..27
    int c  = rest % 7;
    int hl = (rest / 7) & 1;      // 0 = hi bf16, 1 = lo (residual)
    int h  = rest / 14;           // co half
    int n = lane & 15, kq = lane >> 4;
    int co  = h * 16 + n;
    int tau = 4 * c + kq;
    unsigned o[4];
    #pragma unroll
    for (int j = 0; j < 4; ++j) {
        if (tau >= 27) { o[j] = 0u; continue; }
        float w0 = w[(co * 8 + 2 * j) * 27 + tau];
        float w1 = w[(co * 8 + 2 * j + 1) * 27 + tau];
        unsigned short b0 = f2bf(w0), b1 = f2bf(w1);
        if (hl) {
            b0 = f2bf(w0 - bf2f(b0));
            b1 = f2bf(w1 - bf2f(b1));
        }
        o[j] = ((unsigned)b1 << 16) | b0;
    }
    *(i32x4*)(wpk + (((h * 2 + hl) * 7 + c) * 64 + lane) * 4) =
        (i32x4){(int)o[0], (int)o[1], (int)o[2], (int)o[3]};
}

__global__ __launch_bounds__(256, 4) void conv_hs_mfma(
    const float* __restrict__ x, const unsigned* __restrict__ wpk,
    const float* __restrict__ bias, float* __restrict__ ws1, float* __restrict__ ws2,
    unsigned* __restrict__ cnt, const float* __restrict__ gnw,
    const float* __restrict__ gnb, float* __restrict__ out)
{
    __shared__ unsigned xdw[NROW * RS];   // 28.8 KB: [row 36][e*4 + cipair] LINEAR
    __shared__ float s1b[32], s2b[32];
    __shared__ unsigned slast;

    const int tid  = threadIdx.x;
    const int lane = tid & 63;
    const int wv   = tid >> 6;          // wave id = z offset within tile
    const int n    = lane & 15;         // A-row (co_local) / B-col (x)
    const int kq   = lane >> 4;         // k-quarter -> tap 4c+kq

    const int blk = blockIdx.x;
    const int b   = blk / 144;
    const int r0  = blk - b * 144;
    const int zb  = r0 / 12;
    const int yb  = r0 - zb * 12;
    const int z0  = zb * 4, y0 = yb * 4;
    const int z   = z0 + wv;

    if (tid < 32) { s1b[tid] = 0.f; s2b[tid] = 0.f; }

    // A fragments: 28 coalesced 16B loads from the precomputed table.
    i32x4 Ah[2][7], Al[2][7];
    #pragma unroll
    for (int h = 0; h < 2; ++h)
        #pragma unroll
        for (int c = 0; c < 7; ++c) {
            Ah[h][c] = *(const i32x4*)(wpk + (((h * 2 + 0) * 7 + c) * 64 + lane) * 4);
            Al[h][c] = *(const i32x4*)(wpk + (((h * 2 + 1) * 7 + c) * 64 + lane) * 4);
        }

    // C/D layout: row(co_local) = kq*4 + i (+16h), col = n
    float bias_r[8];
    #pragma unroll
    for (int h = 0; h < 2; ++h)
        #pragma unroll
        for (int i = 0; i < 4; ++i)
            bias_r[h * 4 + i] = bias[h * 16 + kq * 4 + i];

    // Per-lane b128 base per chunk: tau = min(4c+kq, 26) (pad slot -> A=0).
    const char* bc[7];
    #pragma unroll
    for (int c = 0; c < 7; ++c) {
        int tau = 4 * c + kq; if (tau > 26) tau = 26;
        const int toff = ((tau / 9) * 6 + ((tau % 9) / 3)) * (RS * 4)
                       + ((tau % 3) + n) * 16;
        bc[c] = (const char*)xdw + wv * (6 * RS * 4) + toff;
    }

    // ---- stage x tile, bf16 ci-pair packed, LINEAR layout ----
    {
        const int q = tid & 3;
        const int e = tid >> 2;            // active e < 48
        if (e < 48) {
            const float* p0 = x + (b * 8 + 2 * q) * IN3 + e;
            const float* p1 = p0 + IN3;
            unsigned* dst = xdw + e * 4 + q;
            #pragma unroll
            for (int zr = 0; zr < 6; ++zr) {
                const int gz = min(z0 + zr, IN - 1);
                #pragma unroll
                for (int yr = 0; yr < 6; ++yr) {
                    const int gy = min(y0 + yr, IN - 1);
                    const int off = gz * IN2 + gy * IN;
                    float f0 = p0[off], f1 = p1[off];
                    dst[(zr * 6 + yr) * RS] = ((unsigned)f2bf(f1) << 16) | f2bf(f0);
                }
            }
        }
    }
    __syncthreads();

    float t1[8] = {0, 0, 0, 0, 0, 0, 0, 0};
    float t2[8] = {0, 0, 0, 0, 0, 0, 0, 0};

    if (z < OUTD) {
        const int ymax = min(4, OUTD - y0);
        for (int y = 0; y < ymax; ++y) {
            const int ybo = y * (RS * 4);
            #pragma unroll
            for (int nt = 0; nt < 3; ++nt) {
                const int col = nt * 16 + n;
                f32x4 a0h = {0, 0, 0, 0}, a0l = {0, 0, 0, 0};
                f32x4 a1h = {0, 0, 0, 0}, a1l = {0, 0, 0, 0};
                __builtin_amdgcn_s_setprio(1);
                #pragma unroll
                for (int c = 0; c < 7; ++c) {
                    i32x4 bd = *(const i32x4*)(bc[c] + ybo + nt * 256);
                    v8s B = __builtin_bit_cast(v8s, bd);
                    a0h = __builtin_amdgcn_mfma_f32_16x16x32_bf16(__builtin_bit_cast(v8s, Ah[0][c]), B, a0h, 0, 0, 0);
                    a1h = __builtin_amdgcn_mfma_f32_16x16x32_bf16(__builtin_bit_cast(v8s, Ah[1][c]), B, a1h, 0, 0, 0);
                    a0l = __builtin_amdgcn_mfma_f32_16x16x32_bf16(__builtin_bit_cast(v8s, Al[0][c]), B, a0l, 0, 0, 0);
                    a1l = __builtin_amdgcn_mfma_f32_16x16x32_bf16(__builtin_bit_cast(v8s, Al[1][c]), B, a1l, 0, 0, 0);
                }
                __builtin_amdgcn_s_setprio(0);
                const bool cok = col < OUTD;
                #pragma unroll
                for (int h = 0; h < 2; ++h) {
                    #pragma unroll
                    for (int i = 0; i < 4; ++i) {
                        float ac = h ? (a1h[i] + a1l[i]) : (a0h[i] + a0l[i]);
                        float v = ac + bias_r[h * 4 + i];
                        float u = fminf(fmaxf(v + 3.0f, 0.0f), 6.0f);
                        float hs = v * u * (1.0f / 6.0f);
                        float hm = cok ? hs : 0.f;
                        t1[h * 4 + i] += hm;
                        t2[h * 4 + i] = fmaf(hm, hm, t2[h * 4 + i]);
                    }
                }
            }
        }
    }

    // reduce over the 16 col-lanes (n); channel set is per-(kq,h,i)
    #pragma unroll
    for (int j = 0; j < 8; ++j) {
        #pragma unroll
        for (int k = 1; k < 16; k <<= 1) {
            t1[j] += __shfl_xor(t1[j], k, 64);
            t2[j] += __shfl_xor(t2[j], k, 64);
        }
    }
    if (n == 0) {
        #pragma unroll
        for (int h = 0; h < 2; ++h)
            #pragma unroll
            for (int i = 0; i < 4; ++i) {
                atomicAdd(&s1b[h * 16 + kq * 4 + i], t1[h * 4 + i]);
                atomicAdd(&s2b[h * 16 + kq * 4 + i], t2[h * 4 + i]);
            }
    }
    __syncthreads();
    if (tid < 32)       atomicAdd(&ws1[b * 32 + tid], s1b[tid]);
    else if (tid < 64)  atomicAdd(&ws2[b * 32 + (tid - 32)], s2b[tid - 32]);

    // ---- last block finalizes GroupNorm + pool (saves a dispatch) ----
    __syncthreads();   // drains this block's ws atomics before cnt bump
    if (tid == 0) {
        __threadfence();
        slast = (atomicAdd(cnt, 1u) == NBLK - 1) ? 1u : 0u;
    }
    __syncthreads();
    if (slast) {
        #pragma unroll
        for (int half = 0; half < 2; ++half) {
            const int idx = tid + half * 256;          // b*32 + c
            const int c = idx & 31;
            float s1 = atomicAdd(&ws1[idx], 0.f);      // device-coherent read
            float s2 = atomicAdd(&ws2[idx], 0.f);
            float g1 = s1, g2 = s2;
            #pragma unroll
            for (int k = 1; k < 8; k <<= 1) {
                g1 += __shfl_xor(g1, k, 64);
                g2 += __shfl_xor(g2, k, 64);
            }
            const float Nsp  = 46.0f * 46.0f * 46.0f;
            const float invN = 1.0f / (8.0f * Nsp);
            float mean = g1 * invN;
            float var  = fmaxf(g2 * invN - mean * mean, 0.0f);
            float rstd = rsqrtf(var + 1e-5f);
            float mc   = s1 * (1.0f / Nsp);
            out[idx] = (mc - mean) * rstd * gnw[c] + gnb[c];
        }
    }
}

extern "C" void kernel_launch(void* const* d_in, const int* in_sizes, int n_in,
                              void* d_out, int out_size, void* d_ws, size_t ws_size,
                              hipStream_t stream) {
    const float* x    = (const float*)d_in[0];
    const float* w    = (const float*)d_in[1];
    const float* bias = (const float*)d_in[2];
    const float* gnw  = (const float*)d_in[3];
    const float* gnb  = (const float*)d_in[4];
    float* out = (float*)d_out;
    float* ws1 = (float*)d_ws;
    float* ws2 = ws1 + 512;
    unsigned* wpk = (unsigned*)d_ws + WPK_OFF;   // 7168 dwords
    unsigned* cnt = (unsigned*)d_ws + CNT_OFF;

    pack_weights<<<dim3(7), dim3(256), 0, stream>>>(w, wpk, ws1);
    conv_hs_mfma<<<dim3(NBLK), dim3(256), 0, stream>>>(
        x, wpk, bias, ws1, ws2, cnt, gnw, gnb, out);
}

// Round 19
// 176.053 us; speedup vs baseline: 3.1329x; 3.1329x over previous
//
#include <hip/hip_runtime.h>

// Conv3d(8->32, k=3, VALID) + bias + HardSwish + GroupNorm(4) + mean pool.
// R14 = R13 with the register cap fixed. R13's launch_bounds(256,4) produced
// VGPR_Count=64 -> catastrophic spill (FETCH 745MB, WRITE 519MB, conv 522us).
// Empirical launch_bounds rule on this compiler (R8/R9/R12/R13 measured):
// arg2=4 -> 64-VGPR cap REGARDLESS of block size; arg2=2 -> 128 cap. Use 2.
// Kept from R13 (both validated): gn_finalize fused into conv's last block
// (2 dispatches, ~10us of fixed overhead), s_setprio(1) around MFMA bursts.
// Base: R12 structure (256 thr, 4z x 4y, 28.8KB LDS, 2304 blocks, one
// ds_read_b128 per K-chunk; conv 69us, VGPR 112, no spill).

#define IN 48
#define IN2 2304
#define IN3 110592
#define OUTD 46
#define RS 200            // row stride in dwords (50 e-slots x 4; overread fits)
#define NROW 36           // 6 z-rows x 6 y-rows
#define WPK_OFF 1024      // dword offset of packed-weight table inside ws
#define CNT_OFF 8192      // dword offset of block-completion counter
#define NBLK (16*12*12)

typedef short v8s   __attribute__((ext_vector_type(8)));
typedef float f32x4 __attribute__((ext_vector_type(4)));
typedef int   i32x4 __attribute__((ext_vector_type(4)));

__device__ __forceinline__ unsigned short f2bf(float f) {
    unsigned u = __builtin_bit_cast(unsigned, f);
    return (unsigned short)((u + 0x7fffu + ((u >> 16) & 1u)) >> 16);   // RNE
}
__device__ __forceinline__ float bf2f(unsigned short h) {
    unsigned u = ((unsigned)h) << 16;
    return __builtin_bit_cast(float, u);
}

// Tap-major A fragments for 16x16x32 (HW-validated R8/R12).
// Layout: [h][hl][c 0..6][lane][4 dw]. Lane: co_local = lane&15,
// kq = lane>>4 -> tau = 4c+kq; dword j = ci pair {2j, 2j+1}. tau>=27 -> 0.
// Also zeroes ws1/ws2 (gid<1024) and cnt (gid==1024).
__global__ __launch_bounds__(256) void pack_weights(
    const float* __restrict__ w, unsigned* __restrict__ wpk,
    float* __restrict__ wsz)
{
    int gid = blockIdx.x * 256 + threadIdx.x;
    if (gid < 1024) wsz[gid] = 0.f;
    if (gid == 1024) ((unsigned*)wsz)[CNT_OFF] = 0u;
    if (gid >= 1792) return;
    int lane = gid & 63;
    int rest = gid >> 6;          // 0..27
    int c  = rest % 7;
    int hl = (rest / 7) & 1;      // 0 = hi bf16, 1 = lo (residual)
    int h  = rest / 14;           // co half
    int n = lane & 15, kq = lane >> 4;
    int co  = h * 16 + n;
    int tau = 4 * c + kq;
    unsigned o[4];
    #pragma unroll
    for (int j = 0; j < 4; ++j) {
        if (tau >= 27) { o[j] = 0u; continue; }
        float w0 = w[(co * 8 + 2 * j) * 27 + tau];
        float w1 = w[(co * 8 + 2 * j + 1) * 27 + tau];
        unsigned short b0 = f2bf(w0), b1 = f2bf(w1);
        if (hl) {
            b0 = f2bf(w0 - bf2f(b0));
            b1 = f2bf(w1 - bf2f(b1));
        }
        o[j] = ((unsigned)b1 << 16) | b0;
    }
    *(i32x4*)(wpk + (((h * 2 + hl) * 7 + c) * 64 + lane) * 4) =
        (i32x4){(int)o[0], (int)o[1], (int)o[2], (int)o[3]};
}

__global__ __launch_bounds__(256, 2) void conv_hs_mfma(
    const float* __restrict__ x, const unsigned* __restrict__ wpk,
    const float* __restrict__ bias, float* __restrict__ ws1, float* __restrict__ ws2,
    unsigned* __restrict__ cnt, const float* __restrict__ gnw,
    const float* __restrict__ gnb, float* __restrict__ out)
{
    __shared__ unsigned xdw[NROW * RS];   // 28.8 KB: [row 36][e*4 + cipair] LINEAR
    __shared__ float s1b[32], s2b[32];
    __shared__ unsigned slast;

    const int tid  = threadIdx.x;
    const int lane = tid & 63;
    const int wv   = tid >> 6;          // wave id = z offset within tile
    const int n    = lane & 15;         // A-row (co_local) / B-col (x)
    const int kq   = lane >> 4;         // k-quarter -> tap 4c+kq

    const int blk = blockIdx.x;
    const int b   = blk / 144;
    const int r0  = blk - b * 144;
    const int zb  = r0 / 12;
    const int yb  = r0 - zb * 12;
    const int z0  = zb * 4, y0 = yb * 4;
    const int z   = z0 + wv;

    if (tid < 32) { s1b[tid] = 0.f; s2b[tid] = 0.f; }

    // A fragments: 28 coalesced 16B loads from the precomputed table.
    i32x4 Ah[2][7], Al[2][7];
    #pragma unroll
    for (int h = 0; h < 2; ++h)
        #pragma unroll
        for (int c = 0; c < 7; ++c) {
            Ah[h][c] = *(const i32x4*)(wpk + (((h * 2 + 0) * 7 + c) * 64 + lane) * 4);
            Al[h][c] = *(const i32x4*)(wpk + (((h * 2 + 1) * 7 + c) * 64 + lane) * 4);
        }

    // C/D layout: row(co_local) = kq*4 + i (+16h), col = n
    float bias_r[8];
    #pragma unroll
    for (int h = 0; h < 2; ++h)
        #pragma unroll
        for (int i = 0; i < 4; ++i)
            bias_r[h * 4 + i] = bias[h * 16 + kq * 4 + i];

    // Per-lane b128 base per chunk: tau = min(4c+kq, 26) (pad slot -> A=0).
    const char* bc[7];
    #pragma unroll
    for (int c = 0; c < 7; ++c) {
        int tau = 4 * c + kq; if (tau > 26) tau = 26;
        const int toff = ((tau / 9) * 6 + ((tau % 9) / 3)) * (RS * 4)
                       + ((tau % 3) + n) * 16;
        bc[c] = (const char*)xdw + wv * (6 * RS * 4) + toff;
    }

    // ---- stage x tile, bf16 ci-pair packed, LINEAR layout ----
    {
        const int q = tid & 3;
        const int e = tid >> 2;            // active e < 48
        if (e < 48) {
            const float* p0 = x + (b * 8 + 2 * q) * IN3 + e;
            const float* p1 = p0 + IN3;
            unsigned* dst = xdw + e * 4 + q;
            #pragma unroll
            for (int zr = 0; zr < 6; ++zr) {
                const int gz = min(z0 + zr, IN - 1);
                #pragma unroll
                for (int yr = 0; yr < 6; ++yr) {
                    const int gy = min(y0 + yr, IN - 1);
                    const int off = gz * IN2 + gy * IN;
                    float f0 = p0[off], f1 = p1[off];
                    dst[(zr * 6 + yr) * RS] = ((unsigned)f2bf(f1) << 16) | f2bf(f0);
                }
            }
        }
    }
    __syncthreads();

    float t1[8] = {0, 0, 0, 0, 0, 0, 0, 0};
    float t2[8] = {0, 0, 0, 0, 0, 0, 0, 0};

    if (z < OUTD) {
        const int ymax = min(4, OUTD - y0);
        for (int y = 0; y < ymax; ++y) {
            const int ybo = y * (RS * 4);
            #pragma unroll
            for (int nt = 0; nt < 3; ++nt) {
                const int col = nt * 16 + n;
                f32x4 a0h = {0, 0, 0, 0}, a0l = {0, 0, 0, 0};
                f32x4 a1h = {0, 0, 0, 0}, a1l = {0, 0, 0, 0};
                __builtin_amdgcn_s_setprio(1);
                #pragma unroll
                for (int c = 0; c < 7; ++c) {
                    i32x4 bd = *(const i32x4*)(bc[c] + ybo + nt * 256);
                    v8s B = __builtin_bit_cast(v8s, bd);
                    a0h = __builtin_amdgcn_mfma_f32_16x16x32_bf16(__builtin_bit_cast(v8s, Ah[0][c]), B, a0h, 0, 0, 0);
                    a1h = __builtin_amdgcn_mfma_f32_16x16x32_bf16(__builtin_bit_cast(v8s, Ah[1][c]), B, a1h, 0, 0, 0);
                    a0l = __builtin_amdgcn_mfma_f32_16x16x32_bf16(__builtin_bit_cast(v8s, Al[0][c]), B, a0l, 0, 0, 0);
                    a1l = __builtin_amdgcn_mfma_f32_16x16x32_bf16(__builtin_bit_cast(v8s, Al[1][c]), B, a1l, 0, 0, 0);
                }
                __builtin_amdgcn_s_setprio(0);
                const bool cok = col < OUTD;
                #pragma unroll
                for (int h = 0; h < 2; ++h) {
                    #pragma unroll
                    for (int i = 0; i < 4; ++i) {
                        float ac = h ? (a1h[i] + a1l[i]) : (a0h[i] + a0l[i]);
                        float v = ac + bias_r[h * 4 + i];
                        float u = fminf(fmaxf(v + 3.0f, 0.0f), 6.0f);
                        float hs = v * u * (1.0f / 6.0f);
                        float hm = cok ? hs : 0.f;
                        t1[h * 4 + i] += hm;
                        t2[h * 4 + i] = fmaf(hm, hm, t2[h * 4 + i]);
                    }
                }
            }
        }
    }

    // reduce over the 16 col-lanes (n); channel set is per-(kq,h,i)
    #pragma unroll
    for (int j = 0; j < 8; ++j) {
        #pragma unroll
        for (int k = 1; k < 16; k <<= 1) {
            t1[j] += __shfl_xor(t1[j], k, 64);
            t2[j] += __shfl_xor(t2[j], k, 64);
        }
    }
    if (n == 0) {
        #pragma unroll
        for (int h = 0; h < 2; ++h)
            #pragma unroll
            for (int i = 0; i < 4; ++i) {
                atomicAdd(&s1b[h * 16 + kq * 4 + i], t1[h * 4 + i]);
                atomicAdd(&s2b[h * 16 + kq * 4 + i], t2[h * 4 + i]);
            }
    }
    __syncthreads();
    if (tid < 32)       atomicAdd(&ws1[b * 32 + tid], s1b[tid]);
    else if (tid < 64)  atomicAdd(&ws2[b * 32 + (tid - 32)], s2b[tid - 32]);

    // ---- last block finalizes GroupNorm + pool (saves a dispatch) ----
    __syncthreads();   // drains this block's ws atomics before cnt bump
    if (tid == 0) {
        __threadfence();
        slast = (atomicAdd(cnt, 1u) == NBLK - 1) ? 1u : 0u;
    }
    __syncthreads();
    if (slast) {
        #pragma unroll
        for (int half = 0; half < 2; ++half) {
            const int idx = tid + half * 256;          // b*32 + c
            const int c = idx & 31;
            float s1 = atomicAdd(&ws1[idx], 0.f);      // device-coherent read
            float s2 = atomicAdd(&ws2[idx], 0.f);
            float g1 = s1, g2 = s2;
            #pragma unroll
            for (int k = 1; k < 8; k <<= 1) {
                g1 += __shfl_xor(g1, k, 64);
                g2 += __shfl_xor(g2, k, 64);
            }
            const float Nsp  = 46.0f * 46.0f * 46.0f;
            const float invN = 1.0f / (8.0f * Nsp);
            float mean = g1 * invN;
            float var  = fmaxf(g2 * invN - mean * mean, 0.0f);
            float rstd = rsqrtf(var + 1e-5f);
            float mc   = s1 * (1.0f / Nsp);
            out[idx] = (mc - mean) * rstd * gnw[c] + gnb[c];
        }
    }
}

extern "C" void kernel_launch(void* const* d_in, const int* in_sizes, int n_in,
                              void* d_out, int out_size, void* d_ws, size_t ws_size,
                              hipStream_t stream) {
    const float* x    = (const float*)d_in[0];
    const float* w    = (const float*)d_in[1];
    const float* bias = (const float*)d_in[2];
    const float* gnw  = (const float*)d_in[3];
    const float* gnb  = (const float*)d_in[4];
    float* out = (float*)d_out;
    float* ws1 = (float*)d_ws;
    float* ws2 = ws1 + 512;
    unsigned* wpk = (unsigned*)d_ws + WPK_OFF;   // 7168 dwords
    unsigned* cnt = (unsigned*)d_ws + CNT_OFF;

    pack_weights<<<dim3(7), dim3(256), 0, stream>>>(w, wpk, ws1);
    conv_hs_mfma<<<dim3(NBLK), dim3(256), 0, stream>>>(
        x, wpk, bias, ws1, ws2, cnt, gnw, gnb, out);
}

// Round 20
// 149.368 us; speedup vs baseline: 3.6926x; 1.1786x over previous
//
#include <hip/hip_runtime.h>

// Conv3d(8->32, k=3, VALID) + bias + HardSwish + GroupNorm(4) + mean pool.
// R15 = R12 base + fused finalize, MINUS the two poisons isolated by the
// R9->R10 / R12->R14 scaling analysis:
//  - __threadfence() REMOVED: on gfx950 agent-scope fence emits buffer_wbl2
//    (L2 writeback) per block; penalty scaled with block count (1152 blk ->
//    +20us, 2304 blk -> +45us). Correctness holds without it: all cross-block
//    comms are device-scope atomics; __syncthreads() drains vmcnt so the cnt
//    bump issues after ws atomics retired at the coherence point.
//  - s_setprio REMOVED: has side-effects in LLVM -> scheduling fence that
//    killed cross-tile pipelining (MfmaUtil 27.6 -> 16.5 in R14).
// Base = R12 (conv 69us): 256 thr, 4z x 4y, 28.8KB LDS, 2304 blocks, one
// ds_read_b128 per K-chunk, launch_bounds(256,2) [arg2=2 -> 128-VGPR cap;
// arg2=4 -> 64 cap = spill, measured R8/R13].

#define IN 48
#define IN2 2304
#define IN3 110592
#define OUTD 46
#define RS 200            // row stride in dwords (50 e-slots x 4; overread fits)
#define NROW 36           // 6 z-rows x 6 y-rows
#define WPK_OFF 1024      // dword offset of packed-weight table inside ws
#define CNT_OFF 8192      // dword offset of block-completion counter
#define NBLK (16*12*12)

typedef short v8s   __attribute__((ext_vector_type(8)));
typedef float f32x4 __attribute__((ext_vector_type(4)));
typedef int   i32x4 __attribute__((ext_vector_type(4)));

__device__ __forceinline__ unsigned short f2bf(float f) {
    unsigned u = __builtin_bit_cast(unsigned, f);
    return (unsigned short)((u + 0x7fffu + ((u >> 16) & 1u)) >> 16);   // RNE
}
__device__ __forceinline__ float bf2f(unsigned short h) {
    unsigned u = ((unsigned)h) << 16;
    return __builtin_bit_cast(float, u);
}

// Tap-major A fragments for 16x16x32 (HW-validated R8/R12).
// Layout: [h][hl][c 0..6][lane][4 dw]. Lane: co_local = lane&15,
// kq = lane>>4 -> tau = 4c+kq; dword j = ci pair {2j, 2j+1}. tau>=27 -> 0.
// Also zeroes ws1/ws2 (gid<1024) and cnt (gid==1024).
__global__ __launch_bounds__(256) void pack_weights(
    const float* __restrict__ w, unsigned* __restrict__ wpk,
    float* __restrict__ wsz)
{
    int gid = blockIdx.x * 256 + threadIdx.x;
    if (gid < 1024) wsz[gid] = 0.f;
    if (gid == 1024) ((unsigned*)wsz)[CNT_OFF] = 0u;
    if (gid >= 1792) return;
    int lane = gid & 63;
    int rest = gid >> 6;          // 0..27
    int c  = rest % 7;
    int hl = (rest / 7) & 1;      // 0 = hi bf16, 1 = lo (residual)
    int h  = rest / 14;           // co half
    int n = lane & 15, kq = lane >> 4;
    int co  = h * 16 + n;
    int tau = 4 * c + kq;
    unsigned o[4];
    #pragma unroll
    for (int j = 0; j < 4; ++j) {
        if (tau >= 27) { o[j] = 0u; continue; }
        float w0 = w[(co * 8 + 2 * j) * 27 + tau];
        float w1 = w[(co * 8 + 2 * j + 1) * 27 + tau];
        unsigned short b0 = f2bf(w0), b1 = f2bf(w1);
        if (hl) {
            b0 = f2bf(w0 - bf2f(b0));
            b1 = f2bf(w1 - bf2f(b1));
        }
        o[j] = ((unsigned)b1 << 16) | b0;
    }
    *(i32x4*)(wpk + (((h * 2 + hl) * 7 + c) * 64 + lane) * 4) =
        (i32x4){(int)o[0], (int)o[1], (int)o[2], (int)o[3]};
}

__global__ __launch_bounds__(256, 2) void conv_hs_mfma(
    const float* __restrict__ x, const unsigned* __restrict__ wpk,
    const float* __restrict__ bias, float* __restrict__ ws1, float* __restrict__ ws2,
    unsigned* __restrict__ cnt, const float* __restrict__ gnw,
    const float* __restrict__ gnb, float* __restrict__ out)
{
    __shared__ unsigned xdw[NROW * RS];   // 28.8 KB: [row 36][e*4 + cipair] LINEAR
    __shared__ float s1b[32], s2b[32];
    __shared__ unsigned slast;

    const int tid  = threadIdx.x;
    const int lane = tid & 63;
    const int wv   = tid >> 6;          // wave id = z offset within tile
    const int n    = lane & 15;         // A-row (co_local) / B-col (x)
    const int kq   = lane >> 4;         // k-quarter -> tap 4c+kq

    const int blk = blockIdx.x;
    const int b   = blk / 144;
    const int r0  = blk - b * 144;
    const int zb  = r0 / 12;
    const int yb  = r0 - zb * 12;
    const int z0  = zb * 4, y0 = yb * 4;
    const int z   = z0 + wv;

    if (tid < 32) { s1b[tid] = 0.f; s2b[tid] = 0.f; }

    // A fragments: 28 coalesced 16B loads from the precomputed table.
    i32x4 Ah[2][7], Al[2][7];
    #pragma unroll
    for (int h = 0; h < 2; ++h)
        #pragma unroll
        for (int c = 0; c < 7; ++c) {
            Ah[h][c] = *(const i32x4*)(wpk + (((h * 2 + 0) * 7 + c) * 64 + lane) * 4);
            Al[h][c] = *(const i32x4*)(wpk + (((h * 2 + 1) * 7 + c) * 64 + lane) * 4);
        }

    // C/D layout: row(co_local) = kq*4 + i (+16h), col = n
    float bias_r[8];
    #pragma unroll
    for (int h = 0; h < 2; ++h)
        #pragma unroll
        for (int i = 0; i < 4; ++i)
            bias_r[h * 4 + i] = bias[h * 16 + kq * 4 + i];

    // Per-lane b128 base per chunk: tau = min(4c+kq, 26) (pad slot -> A=0).
    const char* bc[7];
    #pragma unroll
    for (int c = 0; c < 7; ++c) {
        int tau = 4 * c + kq; if (tau > 26) tau = 26;
        const int toff = ((tau / 9) * 6 + ((tau % 9) / 3)) * (RS * 4)
                       + ((tau % 3) + n) * 16;
        bc[c] = (const char*)xdw + wv * (6 * RS * 4) + toff;
    }

    // ---- stage x tile, bf16 ci-pair packed, LINEAR layout ----
    {
        const int q = tid & 3;
        const int e = tid >> 2;            // active e < 48
        if (e < 48) {
            const float* p0 = x + (b * 8 + 2 * q) * IN3 + e;
            const float* p1 = p0 + IN3;
            unsigned* dst = xdw + e * 4 + q;
            #pragma unroll
            for (int zr = 0; zr < 6; ++zr) {
                const int gz = min(z0 + zr, IN - 1);
                #pragma unroll
                for (int yr = 0; yr < 6; ++yr) {
                    const int gy = min(y0 + yr, IN - 1);
                    const int off = gz * IN2 + gy * IN;
                    float f0 = p0[off], f1 = p1[off];
                    dst[(zr * 6 + yr) * RS] = ((unsigned)f2bf(f1) << 16) | f2bf(f0);
                }
            }
        }
    }
    __syncthreads();

    float t1[8] = {0, 0, 0, 0, 0, 0, 0, 0};
    float t2[8] = {0, 0, 0, 0, 0, 0, 0, 0};

    if (z < OUTD) {
        const int ymax = min(4, OUTD - y0);
        for (int y = 0; y < ymax; ++y) {
            const int ybo = y * (RS * 4);
            #pragma unroll
            for (int nt = 0; nt < 3; ++nt) {
                const int col = nt * 16 + n;
                f32x4 a0h = {0, 0, 0, 0}, a0l = {0, 0, 0, 0};
                f32x4 a1h = {0, 0, 0, 0}, a1l = {0, 0, 0, 0};
                #pragma unroll
                for (int c = 0; c < 7; ++c) {
                    i32x4 bd = *(const i32x4*)(bc[c] + ybo + nt * 256);
                    v8s B = __builtin_bit_cast(v8s, bd);
                    a0h = __builtin_amdgcn_mfma_f32_16x16x32_bf16(__builtin_bit_cast(v8s, Ah[0][c]), B, a0h, 0, 0, 0);
                    a1h = __builtin_amdgcn_mfma_f32_16x16x32_bf16(__builtin_bit_cast(v8s, Ah[1][c]), B, a1h, 0, 0, 0);
                    a0l = __builtin_amdgcn_mfma_f32_16x16x32_bf16(__builtin_bit_cast(v8s, Al[0][c]), B, a0l, 0, 0, 0);
                    a1l = __builtin_amdgcn_mfma_f32_16x16x32_bf16(__builtin_bit_cast(v8s, Al[1][c]), B, a1l, 0, 0, 0);
                }
                const bool cok = col < OUTD;
                #pragma unroll
                for (int h = 0; h < 2; ++h) {
                    #pragma unroll
                    for (int i = 0; i < 4; ++i) {
                        float ac = h ? (a1h[i] + a1l[i]) : (a0h[i] + a0l[i]);
                        float v = ac + bias_r[h * 4 + i];
                        float u = fminf(fmaxf(v + 3.0f, 0.0f), 6.0f);
                        float hs = v * u * (1.0f / 6.0f);
                        float hm = cok ? hs : 0.f;
                        t1[h * 4 + i] += hm;
                        t2[h * 4 + i] = fmaf(hm, hm, t2[h * 4 + i]);
                    }
                }
            }
        }
    }

    // reduce over the 16 col-lanes (n); channel set is per-(kq,h,i)
    #pragma unroll
    for (int j = 0; j < 8; ++j) {
        #pragma unroll
        for (int k = 1; k < 16; k <<= 1) {
            t1[j] += __shfl_xor(t1[j], k, 64);
            t2[j] += __shfl_xor(t2[j], k, 64);
        }
    }
    if (n == 0) {
        #pragma unroll
        for (int h = 0; h < 2; ++h)
            #pragma unroll
            for (int i = 0; i < 4; ++i) {
                atomicAdd(&s1b[h * 16 + kq * 4 + i], t1[h * 4 + i]);
                atomicAdd(&s2b[h * 16 + kq * 4 + i], t2[h * 4 + i]);
            }
    }
    __syncthreads();
    if (tid < 32)       atomicAdd(&ws1[b * 32 + tid], s1b[tid]);
    else if (tid < 64)  atomicAdd(&ws2[b * 32 + (tid - 32)], s2b[tid - 32]);

    // ---- last block finalizes GroupNorm + pool (saves a dispatch) ----
    // NO __threadfence(): ws traffic is device-scope atomics; the barrier's
    // vmcnt(0) drain means they completed at the coherence point before the
    // cnt bump issues. (threadfence = buffer_wbl2 per block = the R14 regression)
    __syncthreads();
    if (tid == 0)
        slast = (atomicAdd(cnt, 1u) == NBLK - 1) ? 1u : 0u;
    __syncthreads();
    if (slast) {
        #pragma unroll
        for (int half = 0; half < 2; ++half) {
            const int idx = tid + half * 256;          // b*32 + c
            const int c = idx & 31;
            float s1 = atomicAdd(&ws1[idx], 0.f);      // device-coherent read
            float s2 = atomicAdd(&ws2[idx], 0.f);
            float g1 = s1, g2 = s2;
            #pragma unroll
            for (int k = 1; k < 8; k <<= 1) {
                g1 += __shfl_xor(g1, k, 64);
                g2 += __shfl_xor(g2, k, 64);
            }
            const float Nsp  = 46.0f * 46.0f * 46.0f;
            const float invN = 1.0f / (8.0f * Nsp);
            float mean = g1 * invN;
            float var  = fmaxf(g2 * invN - mean * mean, 0.0f);
            float rstd = rsqrtf(var + 1e-5f);
            float mc   = s1 * (1.0f / Nsp);
            out[idx] = (mc - mean) * rstd * gnw[c] + gnb[c];
        }
    }
}

extern "C" void kernel_launch(void* const* d_in, const int* in_sizes, int n_in,
                              void* d_out, int out_size, void* d_ws, size_t ws_size,
                              hipStream_t stream) {
    const float* x    = (const float*)d_in[0];
    const float* w    = (const float*)d_in[1];
    const float* bias = (const float*)d_in[2];
    const float* gnw  = (const float*)d_in[3];
    const float* gnb  = (const float*)d_in[4];
    float* out = (float*)d_out;
    float* ws1 = (float*)d_ws;
    float* ws2 = ws1 + 512;
    unsigned* wpk = (unsigned*)d_ws + WPK_OFF;   // 7168 dwords
    unsigned* cnt = (unsigned*)d_ws + CNT_OFF;

    pack_weights<<<dim3(7), dim3(256), 0, stream>>>(w, wpk, ws1);
    conv_hs_mfma<<<dim3(NBLK), dim3(256), 0, stream>>>(
        x, wpk, bias, ws1, ws2, cnt, gnw, gnb, out);
}

// Round 24
// 145.494 us; speedup vs baseline: 3.7909x; 1.0266x over previous
//
#include <hip/hip_runtime.h>

// Conv3d(8->32, k=3, VALID) + bias + HardSwish + GroupNorm(4) + mean pool.
// R16 (resubmit x3; GPU acquisition timeouts, never measured) = R12 (best:
// total 141.8, conv 69.2; 3 dispatches) + 2 tiles per block (grid 2304 ->
// 1152). Fusion REVERTED (R15: cnt-atomic tail +5us conv, no total gain).
// Residency theory: occupancy ~18% (1.5 blocks/CU) despite resources
// allowing 4-5; R13's slow blocks showed 38% -> residency scales with block
// lifetime -> feed-rate-limited. Longer-lived blocks (2 tiles, A-fragments
// amortized) should double overlap of staging with compute.
// Per-rep epilogue: reduce -> barrier -> ws atomics + s-buffer re-zero by the
// reading threads (program order kills the s2b race); rep-1 staging is
// ordered after rep-0 compute by the same barrier.

#define IN 48
#define IN2 2304
#define IN3 110592
#define OUTD 46
#define RS 200            // row stride in dwords (50 e-slots x 4; overread fits)
#define NROW 36           // 6 z-rows x 6 y-rows
#define WPK_OFF 1024      // dword offset of packed-weight table inside ws

typedef short v8s   __attribute__((ext_vector_type(8)));
typedef float f32x4 __attribute__((ext_vector_type(4)));
typedef int   i32x4 __attribute__((ext_vector_type(4)));

__device__ __forceinline__ unsigned short f2bf(float f) {
    unsigned u = __builtin_bit_cast(unsigned, f);
    return (unsigned short)((u + 0x7fffu + ((u >> 16) & 1u)) >> 16);   // RNE
}
__device__ __forceinline__ float bf2f(unsigned short h) {
    unsigned u = ((unsigned)h) << 16;
    return __builtin_bit_cast(float, u);
}

// Tap-major A fragments for 16x16x32 (HW-validated R8/R12).
// Layout: [h][hl][c 0..6][lane][4 dw]. Lane: co_local = lane&15,
// kq = lane>>4 -> tau = 4c+kq; dword j = ci pair {2j, 2j+1}. tau>=27 -> 0.
// Also zeroes ws1/ws2 (gid<1024).
__global__ __launch_bounds__(256) void pack_weights(
    const float* __restrict__ w, unsigned* __restrict__ wpk,
    float* __restrict__ wsz)
{
    int gid = blockIdx.x * 256 + threadIdx.x;
    if (gid < 1024) wsz[gid] = 0.f;
    if (gid >= 1792) return;
    int lane = gid & 63;
    int rest = gid >> 6;          // 0..27
    int c  = rest % 7;
    int hl = (rest / 7) & 1;      // 0 = hi bf16, 1 = lo (residual)
    int h  = rest / 14;           // co half
    int n = lane & 15, kq = lane >> 4;
    int co  = h * 16 + n;
    int tau = 4 * c + kq;
    unsigned o[4];
    #pragma unroll
    for (int j = 0; j < 4; ++j) {
        if (tau >= 27) { o[j] = 0u; continue; }
        float w0 = w[(co * 8 + 2 * j) * 27 + tau];
        float w1 = w[(co * 8 + 2 * j + 1) * 27 + tau];
        unsigned short b0 = f2bf(w0), b1 = f2bf(w1);
        if (hl) {
            b0 = f2bf(w0 - bf2f(b0));
            b1 = f2bf(w1 - bf2f(b1));
        }
        o[j] = ((unsigned)b1 << 16) | b0;
    }
    *(i32x4*)(wpk + (((h * 2 + hl) * 7 + c) * 64 + lane) * 4) =
        (i32x4){(int)o[0], (int)o[1], (int)o[2], (int)o[3]};
}

__global__ __launch_bounds__(256, 2) void conv_hs_mfma(
    const float* __restrict__ x, const unsigned* __restrict__ wpk,
    const float* __restrict__ bias, float* __restrict__ ws1, float* __restrict__ ws2)
{
    __shared__ unsigned xdw[NROW * RS];   // 28.8 KB: [row 36][e*4 + cipair] LINEAR
    __shared__ float s1b[32], s2b[32];

    const int tid  = threadIdx.x;
    const int lane = tid & 63;
    const int wv   = tid >> 6;          // wave id = z offset within tile
    const int n    = lane & 15;         // A-row (co_local) / B-col (x)
    const int kq   = lane >> 4;         // k-quarter -> tap 4c+kq

    if (tid < 32) { s1b[tid] = 0.f; s2b[tid] = 0.f; }

    // A fragments: 28 coalesced 16B loads, ONCE for both reps.
    i32x4 Ah[2][7], Al[2][7];
    #pragma unroll
    for (int h = 0; h < 2; ++h)
        #pragma unroll
        for (int c = 0; c < 7; ++c) {
            Ah[h][c] = *(const i32x4*)(wpk + (((h * 2 + 0) * 7 + c) * 64 + lane) * 4);
            Al[h][c] = *(const i32x4*)(wpk + (((h * 2 + 1) * 7 + c) * 64 + lane) * 4);
        }

    // C/D layout: row(co_local) = kq*4 + i (+16h), col = n
    float bias_r[8];
    #pragma unroll
    for (int h = 0; h < 2; ++h)
        #pragma unroll
        for (int i = 0; i < 4; ++i)
            bias_r[h * 4 + i] = bias[h * 16 + kq * 4 + i];

    // Per-lane b128 base per chunk: tau = min(4c+kq, 26) (pad slot -> A=0).
    const char* bc[7];
    #pragma unroll
    for (int c = 0; c < 7; ++c) {
        int tau = 4 * c + kq; if (tau > 26) tau = 26;
        const int toff = ((tau / 9) * 6 + ((tau % 9) / 3)) * (RS * 4)
                       + ((tau % 3) + n) * 16;
        bc[c] = (const char*)xdw + wv * (6 * RS * 4) + toff;
    }

    for (int rep = 0; rep < 2; ++rep) {
        const int t  = blockIdx.x * 2 + rep;
        const int b  = t / 144;
        const int r0 = t - b * 144;
        const int zb = r0 / 12;
        const int yb = r0 - zb * 12;
        const int z0 = zb * 4, y0 = yb * 4;
        const int z  = z0 + wv;

        // ---- stage x tile, bf16 ci-pair packed, LINEAR layout ----
        // (rep>0: xdw reads of previous tile completed at the epilogue barrier)
        {
            const int q = tid & 3;
            const int e = tid >> 2;            // active e < 48
            if (e < 48) {
                const float* p0 = x + (b * 8 + 2 * q) * IN3 + e;
                const float* p1 = p0 + IN3;
                unsigned* dst = xdw + e * 4 + q;
                #pragma unroll
                for (int zr = 0; zr < 6; ++zr) {
                    const int gz = min(z0 + zr, IN - 1);
                    #pragma unroll
                    for (int yr = 0; yr < 6; ++yr) {
                        const int gy = min(y0 + yr, IN - 1);
                        const int off = gz * IN2 + gy * IN;
                        float f0 = p0[off], f1 = p1[off];
                        dst[(zr * 6 + yr) * RS] = ((unsigned)f2bf(f1) << 16) | f2bf(f0);
                    }
                }
            }
        }
        __syncthreads();

        float t1[8] = {0, 0, 0, 0, 0, 0, 0, 0};
        float t2[8] = {0, 0, 0, 0, 0, 0, 0, 0};

        if (z < OUTD) {
            const int ymax = min(4, OUTD - y0);
            for (int y = 0; y < ymax; ++y) {
                const int ybo = y * (RS * 4);
                #pragma unroll
                for (int nt = 0; nt < 3; ++nt) {
                    const int col = nt * 16 + n;
                    f32x4 a0h = {0, 0, 0, 0}, a0l = {0, 0, 0, 0};
                    f32x4 a1h = {0, 0, 0, 0}, a1l = {0, 0, 0, 0};
                    #pragma unroll
                    for (int c = 0; c < 7; ++c) {
                        i32x4 bd = *(const i32x4*)(bc[c] + ybo + nt * 256);
                        v8s B = __builtin_bit_cast(v8s, bd);
                        a0h = __builtin_amdgcn_mfma_f32_16x16x32_bf16(__builtin_bit_cast(v8s, Ah[0][c]), B, a0h, 0, 0, 0);
                        a1h = __builtin_amdgcn_mfma_f32_16x16x32_bf16(__builtin_bit_cast(v8s, Ah[1][c]), B, a1h, 0, 0, 0);
                        a0l = __builtin_amdgcn_mfma_f32_16x16x32_bf16(__builtin_bit_cast(v8s, Al[0][c]), B, a0l, 0, 0, 0);
                        a1l = __builtin_amdgcn_mfma_f32_16x16x32_bf16(__builtin_bit_cast(v8s, Al[1][c]), B, a1l, 0, 0, 0);
                    }
                    const bool cok = col < OUTD;
                    #pragma unroll
                    for (int h = 0; h < 2; ++h) {
                        #pragma unroll
                        for (int i = 0; i < 4; ++i) {
                            float ac = h ? (a1h[i] + a1l[i]) : (a0h[i] + a0l[i]);
                            float v = ac + bias_r[h * 4 + i];
                            float u = fminf(fmaxf(v + 3.0f, 0.0f), 6.0f);
                            float hs = v * u * (1.0f / 6.0f);
                            float hm = cok ? hs : 0.f;
                            t1[h * 4 + i] += hm;
                            t2[h * 4 + i] = fmaf(hm, hm, t2[h * 4 + i]);
                        }
                    }
                }
            }
        }

        // reduce over the 16 col-lanes (n); channel set is per-(kq,h,i)
        #pragma unroll
        for (int j = 0; j < 8; ++j) {
            #pragma unroll
            for (int k = 1; k < 16; k <<= 1) {
                t1[j] += __shfl_xor(t1[j], k, 64);
                t2[j] += __shfl_xor(t2[j], k, 64);
            }
        }
        if (n == 0) {
            #pragma unroll
            for (int h = 0; h < 2; ++h)
                #pragma unroll
                for (int i = 0; i < 4; ++i) {
                    atomicAdd(&s1b[h * 16 + kq * 4 + i], t1[h * 4 + i]);
                    atomicAdd(&s2b[h * 16 + kq * 4 + i], t2[h * 4 + i]);
                }
        }
        __syncthreads();   // s1b complete; also orders xdw reads before rep+1 staging
        if (tid < 32) {
            atomicAdd(&ws1[b * 32 + tid], s1b[tid]);
            s1b[tid] = 0.f;                    // re-zero by the reading thread
        } else if (tid < 64) {
            atomicAdd(&ws2[b * 32 + (tid - 32)], s2b[tid - 32]);
            s2b[tid - 32] = 0.f;
        }
        // next rep's s1b atomics are ordered after this zeroing by the
        // next rep's post-staging __syncthreads()
    }
}

__global__ __launch_bounds__(512) void gn_finalize(
    const float* __restrict__ ws1, const float* __restrict__ ws2,
    const float* __restrict__ gnw, const float* __restrict__ gnb,
    float* __restrict__ out)
{
    int tid = threadIdx.x;
    int c = tid & 31;
    float s1 = ws1[tid], s2 = ws2[tid];
    float g1 = s1, g2 = s2;
    #pragma unroll
    for (int k = 1; k < 8; k <<= 1) {
        g1 += __shfl_xor(g1, k, 64);
        g2 += __shfl_xor(g2, k, 64);
    }
    const float Nsp  = 46.0f * 46.0f * 46.0f;
    const float invN = 1.0f / (8.0f * Nsp);
    float mean = g1 * invN;
    float var  = fmaxf(g2 * invN - mean * mean, 0.0f);
    float rstd = rsqrtf(var + 1e-5f);
    float mc   = s1 * (1.0f / Nsp);
    out[tid] = (mc - mean) * rstd * gnw[c] + gnb[c];
}

extern "C" void kernel_launch(void* const* d_in, const int* in_sizes, int n_in,
                              void* d_out, int out_size, void* d_ws, size_t ws_size,
                              hipStream_t stream) {
    const float* x    = (const float*)d_in[0];
    const float* w    = (const float*)d_in[1];
    const float* bias = (const float*)d_in[2];
    const float* gnw  = (const float*)d_in[3];
    const float* gnb  = (const float*)d_in[4];
    float* out = (float*)d_out;
    float* ws1 = (float*)d_ws;
    float* ws2 = ws1 + 512;
    unsigned* wpk = (unsigned*)d_ws + WPK_OFF;   // 7168 dwords

    pack_weights<<<dim3(7), dim3(256), 0, stream>>>(w, wpk, ws1);
    conv_hs_mfma<<<dim3(16 * 12 * 6), dim3(256), 0, stream>>>(x, wpk, bias, ws1, ws2);
    gn_finalize<<<dim3(1), dim3(512), 0, stream>>>(ws1, ws2, gnw, gnb, out);
}